// Round 10
// baseline (499.137 us; speedup 1.0000x reference)
//
#include <hip/hip_runtime.h>
#include <math.h>

// Problem constants (from reference setup): T=4, B=64, N=1024, P=63, D=128
#define T_STEPS 4
#define R_ROWS  65536              // B*N rows per timestep
#define M_ROWS  262144             // T*B*N total rows
#define P_DIM   63
#define D_DIM   128
#define PP      64                 // padded P (col 63 = virtual ones column in K1)

#define TILES_TOTAL (M_ROWS / 64)  // 4096 tiles of 64 rows
#define G_CHUNKS 8                 // reduce output copies consumed by stats

typedef float v4f __attribute__((ext_vector_type(4)));

// ---------------------------------------------------------------------------
// K1: per-block partial Gram  P_b = xa_b^T xa_b  (xa = x + ones column).
// (unchanged — isolate the K3 change for clean attribution)
// ---------------------------------------------------------------------------
__global__ __launch_bounds__(256) void gram_kernel(const float* __restrict__ x,
                                                   double* __restrict__ partials,
                                                   int tiles_per_block) {
    __shared__ __align__(16) float xt[2][64 * PP];
    const int tid = threadIdx.x;
    const int tj = tid & 15;       // 16 col-tiles of 4
    const int ti = tid >> 4;       // 16 row-tiles of 4

    double dacc[4][4];
#pragma unroll
    for (int a = 0; a < 4; a++)
#pragma unroll
        for (int b = 0; b < 4; b++) dacc[a][b] = 0.0;

    if (tid < 64) {                // ones column in both buffers (never overwritten)
        xt[0][tid * PP + 63] = 1.0f;
        xt[1][tid * PP + 63] = 1.0f;
    }

    const int tile0 = blockIdx.x * tiles_per_block;
    float4 reg[4];

    {
        const float4* src = (const float4*)(x + (size_t)tile0 * (64 * 63));
#pragma unroll
        for (int it = 0; it < 4; it++) {
            int k = tid + it * 256;
            reg[it] = (k < 1008) ? src[k] : make_float4(0.f, 0.f, 0.f, 0.f);
        }
    }
#pragma unroll
    for (int it = 0; it < 4; it++) {
        int k = tid + it * 256;
        if (k < 1008) {
            const float* ve = (const float*)&reg[it];
            int flat = k * 4;
#pragma unroll
            for (int e = 0; e < 4; e++) {
                int f = flat + e;
                int r = f / 63;
                int c = f - r * 63;
                xt[0][r * PP + c] = ve[e];
            }
        }
    }
    __syncthreads();

    for (int t = 0; t < tiles_per_block; t++) {
        const int cur = t & 1;
        if (t + 1 < tiles_per_block) {
            const float4* src = (const float4*)(x + (size_t)(tile0 + t + 1) * (64 * 63));
#pragma unroll
            for (int it = 0; it < 4; it++) {
                int k = tid + it * 256;
                reg[it] = (k < 1008) ? src[k] : make_float4(0.f, 0.f, 0.f, 0.f);
            }
        }

        float facc[4][4];
#pragma unroll
        for (int a = 0; a < 4; a++)
#pragma unroll
            for (int b = 0; b < 4; b++) facc[a][b] = 0.0f;

        const float* buf = xt[cur];
        for (int r = 0; r < 64; r++) {
            float4 xi = *(const float4*)&buf[r * PP + ti * 4];
            float4 xj = *(const float4*)&buf[r * PP + tj * 4];
            const float* xia = (const float*)&xi;
            const float* xja = (const float*)&xj;
#pragma unroll
            for (int a = 0; a < 4; a++)
#pragma unroll
                for (int b = 0; b < 4; b++)
                    facc[a][b] = fmaf(xia[a], xja[b], facc[a][b]);
        }
#pragma unroll
        for (int a = 0; a < 4; a++)
#pragma unroll
            for (int b = 0; b < 4; b++) dacc[a][b] += (double)facc[a][b];

        __syncthreads();
        if (t + 1 < tiles_per_block) {
            float* nbuf = xt[1 - cur];
#pragma unroll
            for (int it = 0; it < 4; it++) {
                int k = tid + it * 256;
                if (k < 1008) {
                    const float* ve = (const float*)&reg[it];
                    int flat = k * 4;
#pragma unroll
                    for (int e = 0; e < 4; e++) {
                        int f = flat + e;
                        int r = f / 63;
                        int c = f - r * 63;
                        nbuf[r * PP + c] = ve[e];
                    }
                }
            }
            __syncthreads();
        }
    }

    double* Pb = partials + (size_t)blockIdx.x * 4096;
#pragma unroll
    for (int a = 0; a < 4; a++)
#pragma unroll
        for (int b = 0; b < 4; b++)
            Pb[(ti * 4 + a) * 64 + (tj * 4 + b)] = dacc[a][b];
}

// ---------------------------------------------------------------------------
// K1b: fold nparts partials into G_CHUNKS copies (deterministic fp64 sums).
// Blocks >= 128 instead build Wt[p*128+d] = W[d*63+p] (needed by lif; folded
// here to avoid an extra launch — runs in dispatch-parallel with the folds).
// ---------------------------------------------------------------------------
__global__ __launch_bounds__(256) void reduce_kernel(const double* __restrict__ partials,
                                                     double* __restrict__ G8,
                                                     const float* __restrict__ W,
                                                     float* __restrict__ Wt,
                                                     int copies_per_chunk) {
    if (blockIdx.x >= G_CHUNKS * 16) {
        int widx = (blockIdx.x - G_CHUNKS * 16) * 256 + threadIdx.x;
        for (int j = widx; j < P_DIM * D_DIM; j += 8 * 256) {
            int p = j >> 7;
            int d = j & 127;
            Wt[j] = W[d * P_DIM + p];
        }
        return;
    }
    const int chunk = blockIdx.x >> 4;             // 0..7
    const int idx   = (blockIdx.x & 15) * 256 + threadIdx.x;  // 0..4095
    const double* src = partials + (size_t)chunk * copies_per_chunk * 4096;
    double s = 0.0;
    for (int c = 0; c < copies_per_chunk; c++)
        s += src[(size_t)c * 4096 + idx];
    G8[(size_t)chunk * 4096 + idx] = s;
}

// ---------------------------------------------------------------------------
// K2: per-channel stats (unchanged).
// ---------------------------------------------------------------------------
__global__ __launch_bounds__(64) void stats_kernel(const double* __restrict__ G,
                                                   const float* __restrict__ W,
                                                   const float* __restrict__ gamma,
                                                   const float* __restrict__ beta,
                                                   float* __restrict__ stats) {
    const int d = blockIdx.x;    // 0..127
    const int p = threadIdx.x;   // 0..63
    __shared__ float sW[64];
    sW[p] = (p < P_DIM) ? W[d * P_DIM + p] : 0.0f;
    __syncthreads();

    double inner = 0.0;
#pragma unroll
    for (int c = 0; c < G_CHUNKS; c++) {
        const double* Gr = G + (size_t)c * (64 * 64) + p * 64;
        for (int q = 0; q < 64; q++) inner += Gr[q] * (double)sW[q];
    }

    double contrib = (double)sW[p] * inner;   // row 63 has w=0 -> no effect
    double ex2M = contrib;
#pragma unroll
    for (int off = 32; off > 0; off >>= 1) ex2M += __shfl_down(ex2M, off, 64);
    double meanM = __shfl(inner, 63, 64);     // ones-row dot W_d = colsum . W_d

    if (p == 0) {
        double mean = meanM / (double)M_ROWS;
        double ex2  = ex2M  / (double)M_ROWS;
        double var  = ex2 - mean * mean;
        float varf  = (float)var;
        float vpe   = varf + 1e-5f;                 // ref: fp32 var + fp32 eps
        float invstd = (float)(1.0 / sqrt((double)vpe));
        stats[d * 4 + 0] = (float)mean;
        stats[d * 4 + 1] = invstd;
        stats[d * 4 + 2] = gamma[d];
        stats[d * 4 + 3] = beta[d];
    }
}

// ---------------------------------------------------------------------------
// K3 r19: r16 structure with sx staged in TWO T-PAIRS ({0,1} then {2,3}).
// Constraints learned this session:
//   - rest-of-runtime is NOT noise: r0/r16 replicate at 182/183us; every lif
//     variant that raised lif's HBM traffic also raised "rest" (r17 +34).
//     => lif changes must keep HBM footprint identical (x read once).
//   - the allocator mangles multi-phase unrolled structure (r18: P-phase
//     restage -> VGPR 200; r12/r14/r15 same disease).  => keep each compute
//     region structurally identical to r16's single proven loop.
// The t-pair split shrinks sx 16K->8K: block LDS 48.6K->40448B -> 4
// blocks/CU (16 waves vs 12).  x bytes/pattern unchanged (each tile read
// once); sw staging unchanged; acc (32 floats) is the only cross-region
// state, same as r16.  fmaf chain per (row,ch,t) untouched -> h bitwise
// identical.  Diagnostic: VGPR must stay ~92 (blowup >128 = allocator
// disease again -> abandon lif, attack gram).
// ---------------------------------------------------------------------------
#define LIF_ROWS 16
#define SX_STRIDE 64
__global__ __launch_bounds__(256) void lif_kernel(const float* __restrict__ x,
                                                  const float* __restrict__ Wt,
                                                  const float* __restrict__ stats,
                                                  float* __restrict__ out) {
    __shared__ __align__(16) float sw[P_DIM * D_DIM];                // 32256 B
    __shared__ __align__(16) float sx[2 * LIF_ROWS * SX_STRIDE];     //  8192 B
    const int tid = threadIdx.x;

    // stage Wt: flat float4 copy (2016 float4), conflict-free, no div
    {
        const float4* wt4 = (const float4*)Wt;
        float4* sw4 = (float4*)sw;
#pragma unroll
        for (int i = 0; i < 8; i++) {
            int k = tid + i * 256;
            if (k < 2016) sw4[k] = wt4[k];
        }
    }

    const int r0 = blockIdx.x * LIF_ROWS;
    const int td = tid & 31;      // 32 channel-tiles of 4
    const int tr = tid >> 5;      // 8 row-pairs
    const int d0 = td * 4;
    const int rowa = tr * 2;

    float acc[8][4];              // [t*2+i][j] — lives across both t-pair regions
#pragma unroll
    for (int u = 0; u < 8; u++)
#pragma unroll
        for (int j = 0; j < 4; j++) acc[u][j] = 0.0f;

    // ---- two t-pair rounds: stage x for t in {tp*2, tp*2+1}, then compute ----
#pragma unroll
    for (int tp = 0; tp < 2; tp++) {
        if (tp == 1) __syncthreads();   // all waves done reading previous sx

        // stage x for 2 timesteps: 128 threads per t, coalesced nontemporal
        {
            const int seg = tid >> 7;          // 0..1 -> timestep tp*2+seg
            const int sub = tid & 127;
            const v4f* src = (const v4f*)(x + ((size_t)(tp * 2 + seg) * R_ROWS + r0) * P_DIM);
#pragma unroll
            for (int kk = 0; kk < 2; kk++) {
                int k = sub + kk * 128;        // < 256; 252 valid
                v4f v;
                if (k < 252) v = __builtin_nontemporal_load(&src[k]);
                if (k < 252) {
                    int flat = k * 4;
#pragma unroll
                    for (int e = 0; e < 4; e++) {
                        int f = flat + e;
                        int r = f / 63;
                        int c = f - r * 63;
                        sx[(seg * LIF_ROWS + r) * SX_STRIDE + c] = v[e];
                    }
                }
            }
        }
        __syncthreads();

        // compute: 15 p-quads fully unrolled, T=2 (structure == r16 loop)
#pragma unroll
        for (int pq = 0; pq < 15; pq++) {
            const int p = pq * 4;
            float4 w0 = *(const float4*)&sw[(p + 0) * D_DIM + d0];
            float4 w1 = *(const float4*)&sw[(p + 1) * D_DIM + d0];
            float4 w2 = *(const float4*)&sw[(p + 2) * D_DIM + d0];
            float4 w3 = *(const float4*)&sw[(p + 3) * D_DIM + d0];
#pragma unroll
            for (int tl = 0; tl < 2; tl++)
#pragma unroll
                for (int i = 0; i < 2; i++) {
                    float4 xv = *(const float4*)&sx[(tl * LIF_ROWS + rowa + i) * SX_STRIDE + p];
                    float* a = acc[(tp * 2 + tl) * 2 + i];
                    a[0] = fmaf(xv.x, w0.x, a[0]);
                    a[1] = fmaf(xv.x, w0.y, a[1]);
                    a[2] = fmaf(xv.x, w0.z, a[2]);
                    a[3] = fmaf(xv.x, w0.w, a[3]);
                    a[0] = fmaf(xv.y, w1.x, a[0]);
                    a[1] = fmaf(xv.y, w1.y, a[1]);
                    a[2] = fmaf(xv.y, w1.z, a[2]);
                    a[3] = fmaf(xv.y, w1.w, a[3]);
                    a[0] = fmaf(xv.z, w2.x, a[0]);
                    a[1] = fmaf(xv.z, w2.y, a[1]);
                    a[2] = fmaf(xv.z, w2.z, a[2]);
                    a[3] = fmaf(xv.z, w2.w, a[3]);
                    a[0] = fmaf(xv.w, w3.x, a[0]);
                    a[1] = fmaf(xv.w, w3.y, a[1]);
                    a[2] = fmaf(xv.w, w3.z, a[2]);
                    a[3] = fmaf(xv.w, w3.w, a[3]);
                }
        }
        // tail: p = 60, 61, 62 (same ascending order)
#pragma unroll
        for (int p = 60; p < 63; p++) {
            float4 w4 = *(const float4*)&sw[p * D_DIM + d0];
#pragma unroll
            for (int tl = 0; tl < 2; tl++)
#pragma unroll
                for (int i = 0; i < 2; i++) {
                    float xv = sx[(tl * LIF_ROWS + rowa + i) * SX_STRIDE + p];
                    float* a = acc[(tp * 2 + tl) * 2 + i];
                    a[0] = fmaf(xv, w4.x, a[0]);
                    a[1] = fmaf(xv, w4.y, a[1]);
                    a[2] = fmaf(xv, w4.z, a[2]);
                    a[3] = fmaf(xv, w4.w, a[3]);
                }
        }
    }

    // epilogue: BN affine (ref op order) + LIF scan; nontemporal b128 stores
#pragma unroll
    for (int i = 0; i < 2; i++) {
        const int row = r0 + rowa + i;
        float sval[T_STEPS][4];
#pragma unroll
        for (int j = 0; j < 4; j++) {
            float4 st = ((const float4*)stats)[d0 + j];  // mean, invstd, gamma, beta
            float v = 0.0f;
#pragma unroll
            for (int t = 0; t < T_STEPS; t++) {
                float hn = (acc[t * 2 + i][j] - st.x) * st.y;
                hn = hn * st.z;
                hn = hn + st.w;
                v = v + (hn - v) * 0.5f;       // == v + (x-v)/2, exact
                float s = (v >= 1.0f) ? 1.0f : 0.0f;  // (v-1>=0) sign-exact
                sval[t][j] = s;
                if (s != 0.0f) v = 0.0f;       // hard reset
            }
        }
#pragma unroll
        for (int t = 0; t < T_STEPS; t++) {
            v4f o = {sval[t][0], sval[t][1], sval[t][2], sval[t][3]};
            __builtin_nontemporal_store(
                o, (v4f*)&out[((size_t)t * R_ROWS + row) * D_DIM + d0]);
        }
    }
}

// ---------------------------------------------------------------------------
extern "C" void kernel_launch(void* const* d_in, const int* in_sizes, int n_in,
                              void* d_out, int out_size, void* d_ws, size_t ws_size,
                              hipStream_t stream) {
    const float* x     = (const float*)d_in[0];
    const float* W     = (const float*)d_in[1];
    const float* gamma = (const float*)d_in[2];
    const float* beta  = (const float*)d_in[3];
    float* out = (float*)d_out;

    // pick partial count by available workspace (power of 2, 64..512)
    const size_t fixed = (size_t)G_CHUNKS * 4096 * 8 + 2048 + 32768 + 4096;
    int nparts = 512;
    while (nparts > 64 && (size_t)nparts * 4096 * 8 + fixed > ws_size) nparts >>= 1;
    const int tiles_per_block = TILES_TOTAL / nparts;

    double* partials = (double*)d_ws;
    double* G8       = (double*)((char*)d_ws + (size_t)nparts * 4096 * 8);
    float*  stats    = (float*)((char*)G8 + (size_t)G_CHUNKS * 4096 * 8);
    float*  Wt       = (float*)((char*)stats + 2048);

    gram_kernel<<<nparts, 256, 0, stream>>>(x, partials, tiles_per_block);
    reduce_kernel<<<G_CHUNKS * 16 + 8, 256, 0, stream>>>(partials, G8, W, Wt,
                                                         nparts / G_CHUNKS);
    stats_kernel<<<D_DIM, 64, 0, stream>>>(G8, W, gamma, beta, stats);
    lif_kernel<<<R_ROWS / LIF_ROWS, 256, 0, stream>>>(x, Wt, stats, out);
}